// Round 1
// baseline (1039.034 us; speedup 1.0000x reference)
//
#include <hip/hip_runtime.h>

typedef unsigned short u16;
typedef __attribute__((ext_vector_type(4))) float f32x4;
typedef __attribute__((ext_vector_type(8))) short bf16x8;

#define AS1 __attribute__((address_space(1)))
#define AS3 __attribute__((address_space(3)))
#define GLL(gp, lp) __builtin_amdgcn_global_load_lds((const AS1 void*)(gp), (AS3 void*)(lp), 16, 0, 0)

__device__ __forceinline__ float b2f(u16 v) { return __uint_as_float(((unsigned)v) << 16); }
__device__ __forceinline__ u16 f2b(float f) {
  unsigned u = __float_as_uint(f);
  u += 0x7fffu + ((u >> 16) & 1u);
  return (u16)(u >> 16);
}
__device__ __forceinline__ unsigned pack2(float a, float b) {
  return (unsigned)f2b(a) | ((unsigned)f2b(b) << 16);
}
__device__ __forceinline__ float blo(unsigned u) { return __uint_as_float(u << 16); }
__device__ __forceinline__ float bhi(unsigned u) { return __uint_as_float(u & 0xffff0000u); }

// ---------------- bf16 GEMM: C[M,N] = A[M,K] * Bt[N,K]^T + bias, fp32 accum ----------------
// 128x128 tile, BK=64, 4 waves each 64x64, 16x16x32 MFMA, global_load_lds staging,
// XOR-swizzled LDS ([row][chunk^(row&7)] of 16B chunks) for conflict-free ds_read_b128.
__global__ __launch_bounds__(256) void gemm_bt(
    const u16* __restrict__ A, const u16* __restrict__ Bt,
    const float* __restrict__ bias, void* __restrict__ Cv,
    int M, int N, int K, int c_bf16)
{
  __shared__ __align__(16) u16 ldsA[128 * 64];
  __shared__ __align__(16) u16 ldsB[128 * 64];
  int tid = threadIdx.x;
  int wid = tid >> 6, lane = tid & 63;
  int row0 = blockIdx.y << 7;
  int col0 = blockIdx.x << 7;
  int wr = (wid >> 1) << 6, wc = (wid & 1) << 6;

  f32x4 acc[4][4];
#pragma unroll
  for (int i = 0; i < 4; ++i)
#pragma unroll
    for (int j = 0; j < 4; ++j) { f32x4 z = {0.f, 0.f, 0.f, 0.f}; acc[i][j] = z; }

  for (int kt = 0; kt < K; kt += 64) {
#pragma unroll
    for (int q = 0; q < 4; ++q) {
      int inst = (wid << 2) + q;            // 0..15, each covers 1KB of the 16KB tile
      int o = (inst << 10) + (lane << 4);   // byte offset this lane fills
      int r = o >> 7;                       // tile row (128B per row)
      int cs = (o >> 4) & 7;                // stored 16B-chunk
      int cl = cs ^ (r & 7);                // logical chunk (pre-swizzled source)
      int ar = row0 + r; ar = ar < M ? ar : M - 1;
      GLL(A + (size_t)ar * K + kt + (cl << 3), ldsA + (inst << 9));
      int br = col0 + r; br = br < N ? br : N - 1;
      GLL(Bt + (size_t)br * K + kt + (cl << 3), ldsB + (inst << 9));
    }
    __syncthreads();
#pragma unroll
    for (int kk = 0; kk < 2; ++kk) {
      bf16x8 af[4], bg[4];
#pragma unroll
      for (int mi = 0; mi < 4; ++mi) {
        int r = wr + (mi << 4) + (lane & 15);
        int cs = ((kk << 2) + (lane >> 4)) ^ (r & 7);
        af[mi] = *(const bf16x8*)(ldsA + (r << 6) + (cs << 3));
      }
#pragma unroll
      for (int ni = 0; ni < 4; ++ni) {
        int r = wc + (ni << 4) + (lane & 15);
        int cs = ((kk << 2) + (lane >> 4)) ^ (r & 7);
        bg[ni] = *(const bf16x8*)(ldsB + (r << 6) + (cs << 3));
      }
#pragma unroll
      for (int mi = 0; mi < 4; ++mi)
#pragma unroll
        for (int ni = 0; ni < 4; ++ni)
          acc[mi][ni] = __builtin_amdgcn_mfma_f32_16x16x32_bf16(af[mi], bg[ni], acc[mi][ni], 0, 0, 0);
    }
    __syncthreads();
  }

#pragma unroll
  for (int mi = 0; mi < 4; ++mi) {
    int rb = row0 + wr + (mi << 4) + ((lane >> 4) << 2);
#pragma unroll
    for (int ni = 0; ni < 4; ++ni) {
      int c = col0 + wc + (ni << 4) + (lane & 15);
      float bv = bias ? bias[c] : 0.f;
#pragma unroll
      for (int j = 0; j < 4; ++j) {
        int r = rb + j;
        if (r < M) {
          float v = acc[mi][ni][j] + bv;
          if (c_bf16) ((u16*)Cv)[(size_t)r * N + c] = f2b(v);
          else ((float*)Cv)[(size_t)r * N + c] = v;
        }
      }
    }
  }
}

// ---------------- window attention: 1 wave per (window, head) ----------------
__global__ __launch_bounds__(64) void win_attn(const u16* __restrict__ qkv, u16* __restrict__ oat)
{
  __shared__ float Ks[49 * 33];
  __shared__ float Vs[49 * 33];
  __shared__ float Ss[49 * 53];
  int lane = threadIdx.x;
  int w = blockIdx.x >> 4, h = blockIdx.x & 15;
  int b = w >> 8, wh = (w >> 4) & 15, ww = w & 15;
  bool act = lane < 49;
  int l = act ? lane : 0;
  int n = (wh * 7 + l / 7) * 112 + (ww * 7 + l % 7);
  const u16* qp = qkv + ((size_t)(b * 12544 + n)) * 1536 + h * 32;
  if (act) {
#pragma unroll
    for (int t = 0; t < 4; ++t) {
      uint4 uk = *(const uint4*)(qp + 512 + t * 8);
      uint4 uv = *(const uint4*)(qp + 1024 + t * 8);
      int o = lane * 33 + t * 8;
      Ks[o + 0] = blo(uk.x); Ks[o + 1] = bhi(uk.x); Ks[o + 2] = blo(uk.y); Ks[o + 3] = bhi(uk.y);
      Ks[o + 4] = blo(uk.z); Ks[o + 5] = bhi(uk.z); Ks[o + 6] = blo(uk.w); Ks[o + 7] = bhi(uk.w);
      Vs[o + 0] = blo(uv.x); Vs[o + 1] = bhi(uv.x); Vs[o + 2] = blo(uv.y); Vs[o + 3] = bhi(uv.y);
      Vs[o + 4] = blo(uv.z); Vs[o + 5] = bhi(uv.z); Vs[o + 6] = blo(uv.w); Vs[o + 7] = bhi(uv.w);
    }
  }
  __syncthreads();
  if (!act) return;
  float q[32];
#pragma unroll
  for (int t = 0; t < 4; ++t) {
    uint4 uq = *(const uint4*)(qp + t * 8);
    q[t * 8 + 0] = blo(uq.x); q[t * 8 + 1] = bhi(uq.x); q[t * 8 + 2] = blo(uq.y); q[t * 8 + 3] = bhi(uq.y);
    q[t * 8 + 4] = blo(uq.z); q[t * 8 + 5] = bhi(uq.z); q[t * 8 + 6] = blo(uq.w); q[t * 8 + 7] = bhi(uq.w);
  }
  const float scale = 0.17677669529663687f;  // 1/sqrt(32)
  float mx = -1e30f;
  for (int j = 0; j < 49; ++j) {
    float s = 0.f;
#pragma unroll
    for (int d = 0; d < 32; ++d) s += q[d] * Ks[j * 33 + d];
    s *= scale;
    Ss[lane * 53 + j] = s;
    mx = fmaxf(mx, s);
  }
  float o[32];
#pragma unroll
  for (int d = 0; d < 32; ++d) o[d] = 0.f;
  float sum = 0.f;
  for (int j = 0; j < 49; ++j) {
    float p = __expf(Ss[lane * 53 + j] - mx);
    sum += p;
#pragma unroll
    for (int d = 0; d < 32; ++d) o[d] += p * Vs[j * 33 + d];
  }
  float inv = 1.f / sum;
  u16* op = oat + ((size_t)(b * 12544 + n)) * 512 + h * 32;
#pragma unroll
  for (int t = 0; t < 4; ++t) {
    uint4 u;
    u.x = pack2(o[t * 8 + 0] * inv, o[t * 8 + 1] * inv);
    u.y = pack2(o[t * 8 + 2] * inv, o[t * 8 + 3] * inv);
    u.z = pack2(o[t * 8 + 4] * inv, o[t * 8 + 5] * inv);
    u.w = pack2(o[t * 8 + 6] * inv, o[t * 8 + 7] * inv);
    *(uint4*)(op + t * 8) = u;
  }
}

// ---------------- DCT of 8x8 patches at subsampled positions -> F2 (3136 x 192) bf16 ----------------
__global__ __launch_bounds__(192) void dct_f2(const float* __restrict__ patches, u16* __restrict__ F2)
{
  __shared__ float pv[192];
  __shared__ float Bm[64];
  int blk = blockIdx.x;
  int b = blk / 784, rem = blk % 784;
  int n = ((rem / 28) * 4) * 112 + (rem % 28) * 4;
  int t = threadIdx.x;
  if (t < 64) {
    int k = t >> 3, ii = t & 7;
    float v = cosf(3.14159265358979323846f * (ii + 0.5f) * (float)k * 0.125f) * 0.5f;
    if (k == 0) v *= 0.70710678118654752f;
    Bm[t] = v;  // Bm[k*8 + i]
  }
  pv[t] = patches[((size_t)b * 192 + t) * 12544 + n];
  __syncthreads();
  int c = t >> 6, fi = (t >> 3) & 7, fk = t & 7;
  float acc = 0.f;
#pragma unroll
  for (int mm = 0; mm < 8; ++mm) {
    float g = 0.f;
#pragma unroll
    for (int jj = 0; jj < 8; ++jj) g += pv[c * 64 + mm * 8 + jj] * Bm[jj * 8 + fk];
    acc += Bm[fi * 8 + mm] * g;
  }
  F2[(size_t)blk * 192 + t] = f2b(acc);
}

// ---------------- spectral attention: 1 block per (batch, query row), 784 keys ----------------
__global__ __launch_bounds__(256) void spec_attn(const u16* __restrict__ qkvs, u16* __restrict__ sopre)
{
  __shared__ float qrow[512];
  __shared__ float sc[784];
  __shared__ float red[4];
  int b = blockIdx.x / 784, qi = blockIdx.x % 784;
  int t = threadIdx.x;
  int lane = t & 63, wid = t >> 6;
  const u16* qb = qkvs + (size_t)(b * 784 + qi) * 1536;
  for (int d = t; d < 512; d += 256) qrow[d] = b2f(qb[d]);
  __syncthreads();
  const float scale = 0.044194173824159216f;  // 1/sqrt(512)
  for (int k = t; k < 784; k += 256) {
    const u16* kr = qkvs + (size_t)(b * 784 + k) * 1536 + 512;
    float s = 0.f;
    for (int d = 0; d < 512; d += 8) {
      uint4 u = *(const uint4*)(kr + d);
      s += qrow[d + 0] * blo(u.x) + qrow[d + 1] * bhi(u.x)
         + qrow[d + 2] * blo(u.y) + qrow[d + 3] * bhi(u.y)
         + qrow[d + 4] * blo(u.z) + qrow[d + 5] * bhi(u.z)
         + qrow[d + 6] * blo(u.w) + qrow[d + 7] * bhi(u.w);
    }
    sc[k] = s * scale;
  }
  __syncthreads();
  float m = -1e30f;
  for (int k = t; k < 784; k += 256) m = fmaxf(m, sc[k]);
#pragma unroll
  for (int ofs = 32; ofs > 0; ofs >>= 1) m = fmaxf(m, __shfl_xor(m, ofs));
  if (lane == 0) red[wid] = m;
  __syncthreads();
  m = fmaxf(fmaxf(red[0], red[1]), fmaxf(red[2], red[3]));
  __syncthreads();  // all reads of red done before reuse
  float sum = 0.f;
  for (int k = t; k < 784; k += 256) { float e = __expf(sc[k] - m); sc[k] = e; sum += e; }
#pragma unroll
  for (int ofs = 32; ofs > 0; ofs >>= 1) sum += __shfl_xor(sum, ofs);
  if (lane == 0) red[wid] = sum;
  __syncthreads();
  sum = red[0] + red[1] + red[2] + red[3];
  float inv = 1.f / sum;
  float o0 = 0.f, o1 = 0.f;
  const u16* vb = qkvs + (size_t)b * 784 * 1536 + 1024 + t * 2;
  for (int k = 0; k < 784; ++k) {
    float p = sc[k];
    unsigned u = *(const unsigned*)(vb + (size_t)k * 1536);
    o0 += p * blo(u); o1 += p * bhi(u);
  }
  *(unsigned*)(sopre + (size_t)(b * 784 + qi) * 512 + t * 2) = pack2(o0 * inv, o1 * inv);
}

// ---------------- combine + nearest-upsample gather + LayerNorm ----------------
__global__ __launch_bounds__(256) void combine_ln(
    const float* __restrict__ tokens, const u16* __restrict__ sp,
    const float* __restrict__ so, const float* __restrict__ alpha,
    float* __restrict__ out)
{
  int nidx = blockIdx.x;
  int b = nidx / 12544, pos = nidx % 12544;
  int i = pos / 112, j = pos % 112;
  const float* tr = tokens + (size_t)nidx * 512;
  const u16* sr = sp + (size_t)nidx * 512;
  const float* qr = so + (size_t)(b * 784 + (i >> 2) * 28 + (j >> 2)) * 512;
  float al = 1.f / (1.f + __expf(-alpha[0]));
  float be = 1.f - al;
  int t = threadIdx.x;
  float x0 = tr[t] + al * b2f(sr[t]) + be * qr[t];
  float x1 = tr[t + 256] + al * b2f(sr[t + 256]) + be * qr[t + 256];
  float s = x0 + x1, ss = x0 * x0 + x1 * x1;
#pragma unroll
  for (int ofs = 32; ofs > 0; ofs >>= 1) { s += __shfl_xor(s, ofs); ss += __shfl_xor(ss, ofs); }
  __shared__ float rs[4], rq[4];
  int lane = t & 63, wid = t >> 6;
  if (lane == 0) { rs[wid] = s; rq[wid] = ss; }
  __syncthreads();
  s = rs[0] + rs[1] + rs[2] + rs[3];
  ss = rq[0] + rq[1] + rq[2] + rq[3];
  float mu = s * 0.001953125f;
  float var = ss * 0.001953125f - mu * mu;
  float rstd = rsqrtf(var + 1e-5f);
  float* orow = out + (size_t)nidx * 512;
  orow[t] = (x0 - mu) * rstd;
  orow[t + 256] = (x1 - mu) * rstd;
}

// ---------------- small prep kernels ----------------
__global__ __launch_bounds__(256) void transT(const float* __restrict__ src, u16* __restrict__ dst, int K, int Nc)
{
  int idx = blockIdx.x * 256 + threadIdx.x;
  if (idx >= K * Nc) return;
  int nn = idx / K, kk = idx % K;
  dst[idx] = f2b(src[(size_t)kk * Nc + nn]);
}

__global__ __launch_bounds__(256) void cvtbf(const float* __restrict__ src, u16* __restrict__ dst)
{
  size_t i = ((size_t)blockIdx.x * 256 + threadIdx.x) * 4;
  float4 v = *(const float4*)(src + i);
  uint2 u;
  u.x = pack2(v.x, v.y);
  u.y = pack2(v.z, v.w);
  *(uint2*)(dst + i) = u;
}

__global__ __launch_bounds__(256) void stack_bias(
    const float* bq_, const float* bk_, const float* bv_,
    const float* bsq_, const float* bsk_, const float* bsv_,
    float* bqkv, float* bsqkv)
{
  int i = blockIdx.x * 256 + threadIdx.x;
  if (i >= 1536) return;
  int r = i & 511;
  bqkv[i]  = (i < 512) ? bq_[r]  : (i < 1024) ? bk_[r]  : bv_[r];
  bsqkv[i] = (i < 512) ? bsq_[r] : (i < 1024) ? bsk_[r] : bsv_[r];
}

// ---------------- launch ----------------
extern "C" void kernel_launch(void* const* d_in, const int* in_sizes, int n_in,
                              void* d_out, int out_size, void* d_ws, size_t ws_size,
                              hipStream_t stream) {
  (void)in_sizes; (void)n_in; (void)out_size; (void)ws_size;
  const float* tokens = (const float*)d_in[0];
  const float* patches = (const float*)d_in[1];
  const float* Wq  = (const float*)d_in[2];
  const float* bq  = (const float*)d_in[3];
  const float* Wk  = (const float*)d_in[4];
  const float* bk  = (const float*)d_in[5];
  const float* Wv  = (const float*)d_in[6];
  const float* bv  = (const float*)d_in[7];
  const float* Wo  = (const float*)d_in[8];
  const float* bo  = (const float*)d_in[9];
  const float* Wsp = (const float*)d_in[10];
  const float* bsp = (const float*)d_in[11];
  const float* Wsq = (const float*)d_in[12];
  const float* bsq = (const float*)d_in[13];
  const float* Wsk = (const float*)d_in[14];
  const float* bsk = (const float*)d_in[15];
  const float* Wsv = (const float*)d_in[16];
  const float* bsv = (const float*)d_in[17];
  const float* Wso = (const float*)d_in[18];
  const float* bso = (const float*)d_in[19];
  const float* alpha = (const float*)d_in[20];
  float* out = (float*)d_out;

  char* ws = (char*)d_ws;
  u16* tokbf  = (u16*)ws;                       // 50176x512 bf16 (later: o_attn)
  u16* qkv    = (u16*)(ws + 51380224);          // 50176x1536 bf16 (later: sp_out 50176x512)
  char* pp    = ws + 51380224 + 154140672;
  u16* WqkvT  = (u16*)pp; pp += 1572864;
  u16* WoT    = (u16*)pp; pp += 524288;
  u16* WsqkvT = (u16*)pp; pp += 1572864;
  u16* WsoT   = (u16*)pp; pp += 524288;
  u16* WspT   = (u16*)pp; pp += 196608;
  float* bqkv = (float*)pp; pp += 6144;
  float* bsqkv= (float*)pp; pp += 6144;
  u16* F2b    = (u16*)pp; pp += 1204224;        // 3136x192 bf16
  u16* sd     = (u16*)pp; pp += 3211264;        // 3136x512 bf16
  u16* qkvs   = (u16*)pp; pp += 9633792;        // 3136x1536 bf16
  u16* sopre  = (u16*)pp; pp += 3211264;        // 3136x512 bf16
  float* sofin= (float*)pp; pp += 6422528;      // 3136x512 f32

  // prep
  cvtbf<<<25088, 256, 0, stream>>>(tokens, tokbf);
  transT<<<1024, 256, 0, stream>>>(Wq, WqkvT, 512, 512);
  transT<<<1024, 256, 0, stream>>>(Wk, WqkvT + 262144, 512, 512);
  transT<<<1024, 256, 0, stream>>>(Wv, WqkvT + 524288, 512, 512);
  transT<<<1024, 256, 0, stream>>>(Wo, WoT, 512, 512);
  transT<<<1024, 256, 0, stream>>>(Wsq, WsqkvT, 512, 512);
  transT<<<1024, 256, 0, stream>>>(Wsk, WsqkvT + 262144, 512, 512);
  transT<<<1024, 256, 0, stream>>>(Wsv, WsqkvT + 524288, 512, 512);
  transT<<<1024, 256, 0, stream>>>(Wso, WsoT, 512, 512);
  transT<<<384, 256, 0, stream>>>(Wsp, WspT, 192, 512);
  stack_bias<<<6, 256, 0, stream>>>(bq, bk, bv, bsq, bsk, bsv, bqkv, bsqkv);

  // spatial path
  gemm_bt<<<dim3(12, 392), 256, 0, stream>>>(tokbf, WqkvT, bqkv, qkv, 50176, 1536, 512, 1);
  win_attn<<<16384, 64, 0, stream>>>(qkv, tokbf);
  gemm_bt<<<dim3(4, 392), 256, 0, stream>>>(tokbf, WoT, bo, qkv, 50176, 512, 512, 1);

  // spectral path (only subsampled 3136 positions matter)
  dct_f2<<<3136, 192, 0, stream>>>(patches, F2b);
  gemm_bt<<<dim3(4, 25), 256, 0, stream>>>(F2b, WspT, bsp, sd, 3136, 512, 192, 1);
  gemm_bt<<<dim3(12, 25), 256, 0, stream>>>(sd, WsqkvT, bsqkv, qkvs, 3136, 1536, 512, 1);
  spec_attn<<<3136, 256, 0, stream>>>(qkvs, sopre);
  gemm_bt<<<dim3(4, 25), 256, 0, stream>>>(sopre, WsoT, bso, sofin, 3136, 512, 512, 0);

  // combine + LN
  combine_ln<<<50176, 256, 0, stream>>>(tokens, qkv, sofin, alpha, out);
}

// Round 2
// 731.253 us; speedup vs baseline: 1.4209x; 1.4209x over previous
//
#include <hip/hip_runtime.h>

typedef unsigned short u16;
typedef __attribute__((ext_vector_type(4))) float f32x4;
typedef __attribute__((ext_vector_type(8))) short bf16x8;

#define AS1 __attribute__((address_space(1)))
#define AS3 __attribute__((address_space(3)))
#define GLL(gp, lp) __builtin_amdgcn_global_load_lds((const AS1 void*)(gp), (AS3 void*)(lp), 16, 0, 0)

__device__ __forceinline__ float b2f(u16 v) { return __uint_as_float(((unsigned)v) << 16); }
__device__ __forceinline__ u16 f2b(float f) {
  unsigned u = __float_as_uint(f);
  u += 0x7fffu + ((u >> 16) & 1u);
  return (u16)(u >> 16);
}
__device__ __forceinline__ unsigned pack2(float a, float b) {
  return (unsigned)f2b(a) | ((unsigned)f2b(b) << 16);
}
__device__ __forceinline__ float blo(unsigned u) { return __uint_as_float(u << 16); }
__device__ __forceinline__ float bhi(unsigned u) { return __uint_as_float(u & 0xffff0000u); }

// ---------------- bf16 GEMM: C[M,N] = A[M,K] * Bt[N,K]^T + bias, fp32 accum ----------------
// 128x128 tile, BK=64, 4 waves each 64x64, 16x16x32 MFMA, global_load_lds staging,
// XOR-swizzled LDS ([row][chunk^(row&7)] of 16B chunks) for conflict-free ds_read_b128.
// Generalized: row strides lda/ldb/ldc, per-batch strides (blockIdx.z), N-edge guards.
__global__ __launch_bounds__(256) void gemm_bt(
    const u16* __restrict__ A, int lda, long sAb,
    const u16* __restrict__ Bt, int ldb, long sBb,
    const float* __restrict__ bias, void* __restrict__ Cv, int ldc, long sCb,
    int M, int N, int K, int c_bf16)
{
  __shared__ __align__(16) u16 ldsA[128 * 64];
  __shared__ __align__(16) u16 ldsB[128 * 64];
  int tid = threadIdx.x;
  int wid = tid >> 6, lane = tid & 63;
  int row0 = blockIdx.y << 7;
  int col0 = blockIdx.x << 7;
  int bz = blockIdx.z;
  A += (size_t)bz * sAb;
  Bt += (size_t)bz * sBb;
  int wr = (wid >> 1) << 6, wc = (wid & 1) << 6;

  f32x4 acc[4][4];
#pragma unroll
  for (int i = 0; i < 4; ++i)
#pragma unroll
    for (int j = 0; j < 4; ++j) { f32x4 z = {0.f, 0.f, 0.f, 0.f}; acc[i][j] = z; }

  for (int kt = 0; kt < K; kt += 64) {
#pragma unroll
    for (int q = 0; q < 4; ++q) {
      int inst = (wid << 2) + q;            // 0..15, each covers 1KB of the 16KB tile
      int o = (inst << 10) + (lane << 4);   // byte offset this lane fills
      int r = o >> 7;                       // tile row (128B per row)
      int cs = (o >> 4) & 7;                // stored 16B-chunk
      int cl = cs ^ (r & 7);                // logical chunk (pre-swizzled source)
      int ar = row0 + r; ar = ar < M ? ar : M - 1;
      GLL(A + (size_t)ar * lda + kt + (cl << 3), ldsA + (inst << 9));
      int br = col0 + r; br = br < N ? br : N - 1;
      GLL(Bt + (size_t)br * ldb + kt + (cl << 3), ldsB + (inst << 9));
    }
    __syncthreads();
#pragma unroll
    for (int kk = 0; kk < 2; ++kk) {
      bf16x8 af[4], bg[4];
#pragma unroll
      for (int mi = 0; mi < 4; ++mi) {
        int r = wr + (mi << 4) + (lane & 15);
        int cs = ((kk << 2) + (lane >> 4)) ^ (r & 7);
        af[mi] = *(const bf16x8*)(ldsA + (r << 6) + (cs << 3));
      }
#pragma unroll
      for (int ni = 0; ni < 4; ++ni) {
        int r = wc + (ni << 4) + (lane & 15);
        int cs = ((kk << 2) + (lane >> 4)) ^ (r & 7);
        bg[ni] = *(const bf16x8*)(ldsB + (r << 6) + (cs << 3));
      }
#pragma unroll
      for (int mi = 0; mi < 4; ++mi)
#pragma unroll
        for (int ni = 0; ni < 4; ++ni)
          acc[mi][ni] = __builtin_amdgcn_mfma_f32_16x16x32_bf16(af[mi], bg[ni], acc[mi][ni], 0, 0, 0);
    }
    __syncthreads();
  }

#pragma unroll
  for (int mi = 0; mi < 4; ++mi) {
    int rb = row0 + wr + (mi << 4) + ((lane >> 4) << 2);
#pragma unroll
    for (int ni = 0; ni < 4; ++ni) {
      int c = col0 + wc + (ni << 4) + (lane & 15);
      float bv = (bias && c < N) ? bias[c] : 0.f;
#pragma unroll
      for (int j = 0; j < 4; ++j) {
        int r = rb + j;
        if (r < M && c < N) {
          float v = acc[mi][ni][j] + bv;
          if (c_bf16) ((u16*)Cv)[(size_t)bz * sCb + (size_t)r * ldc + c] = f2b(v);
          else ((float*)Cv)[(size_t)bz * sCb + (size_t)r * ldc + c] = v;
        }
      }
    }
  }
}

// ---------------- window attention: 1 wave per (window, head) ----------------
__global__ __launch_bounds__(64) void win_attn(const u16* __restrict__ qkv, u16* __restrict__ oat)
{
  __shared__ float Ks[49 * 33];
  __shared__ float Vs[49 * 33];
  __shared__ float Ss[49 * 53];
  int lane = threadIdx.x;
  int w = blockIdx.x >> 4, h = blockIdx.x & 15;
  int b = w >> 8, wh = (w >> 4) & 15, ww = w & 15;
  bool act = lane < 49;
  int l = act ? lane : 0;
  int n = (wh * 7 + l / 7) * 112 + (ww * 7 + l % 7);
  const u16* qp = qkv + ((size_t)(b * 12544 + n)) * 1536 + h * 32;
  if (act) {
#pragma unroll
    for (int t = 0; t < 4; ++t) {
      uint4 uk = *(const uint4*)(qp + 512 + t * 8);
      uint4 uv = *(const uint4*)(qp + 1024 + t * 8);
      int o = lane * 33 + t * 8;
      Ks[o + 0] = blo(uk.x); Ks[o + 1] = bhi(uk.x); Ks[o + 2] = blo(uk.y); Ks[o + 3] = bhi(uk.y);
      Ks[o + 4] = blo(uk.z); Ks[o + 5] = bhi(uk.z); Ks[o + 6] = blo(uk.w); Ks[o + 7] = bhi(uk.w);
      Vs[o + 0] = blo(uv.x); Vs[o + 1] = bhi(uv.x); Vs[o + 2] = blo(uv.y); Vs[o + 3] = bhi(uv.y);
      Vs[o + 4] = blo(uv.z); Vs[o + 5] = bhi(uv.z); Vs[o + 6] = blo(uv.w); Vs[o + 7] = bhi(uv.w);
    }
  }
  __syncthreads();
  if (!act) return;
  float q[32];
#pragma unroll
  for (int t = 0; t < 4; ++t) {
    uint4 uq = *(const uint4*)(qp + t * 8);
    q[t * 8 + 0] = blo(uq.x); q[t * 8 + 1] = bhi(uq.x); q[t * 8 + 2] = blo(uq.y); q[t * 8 + 3] = bhi(uq.y);
    q[t * 8 + 4] = blo(uq.z); q[t * 8 + 5] = bhi(uq.z); q[t * 8 + 6] = blo(uq.w); q[t * 8 + 7] = bhi(uq.w);
  }
  const float scale = 0.17677669529663687f;  // 1/sqrt(32)
  float mx = -1e30f;
  for (int j = 0; j < 49; ++j) {
    float s = 0.f;
#pragma unroll
    for (int d = 0; d < 32; ++d) s += q[d] * Ks[j * 33 + d];
    s *= scale;
    Ss[lane * 53 + j] = s;
    mx = fmaxf(mx, s);
  }
  float o[32];
#pragma unroll
  for (int d = 0; d < 32; ++d) o[d] = 0.f;
  float sum = 0.f;
  for (int j = 0; j < 49; ++j) {
    float p = __expf(Ss[lane * 53 + j] - mx);
    sum += p;
#pragma unroll
    for (int d = 0; d < 32; ++d) o[d] += p * Vs[j * 33 + d];
  }
  float inv = 1.f / sum;
  u16* op = oat + ((size_t)(b * 12544 + n)) * 512 + h * 32;
#pragma unroll
  for (int t = 0; t < 4; ++t) {
    uint4 u;
    u.x = pack2(o[t * 8 + 0] * inv, o[t * 8 + 1] * inv);
    u.y = pack2(o[t * 8 + 2] * inv, o[t * 8 + 3] * inv);
    u.z = pack2(o[t * 8 + 4] * inv, o[t * 8 + 5] * inv);
    u.w = pack2(o[t * 8 + 6] * inv, o[t * 8 + 7] * inv);
    *(uint4*)(op + t * 8) = u;
  }
}

// ---------------- DCT of 8x8 patches at subsampled positions -> F2 (3136 x 192) bf16 ----------------
__global__ __launch_bounds__(192) void dct_f2(const float* __restrict__ patches, u16* __restrict__ F2)
{
  __shared__ float pv[192];
  __shared__ float Bm[64];
  int blk = blockIdx.x;
  int b = blk / 784, rem = blk % 784;
  int n = ((rem / 28) * 4) * 112 + (rem % 28) * 4;
  int t = threadIdx.x;
  if (t < 64) {
    int k = t >> 3, ii = t & 7;
    float v = cosf(3.14159265358979323846f * (ii + 0.5f) * (float)k * 0.125f) * 0.5f;
    if (k == 0) v *= 0.70710678118654752f;
    Bm[t] = v;  // Bm[k*8 + i]
  }
  pv[t] = patches[((size_t)b * 192 + t) * 12544 + n];
  __syncthreads();
  int c = t >> 6, fi = (t >> 3) & 7, fk = t & 7;
  float acc = 0.f;
#pragma unroll
  for (int mm = 0; mm < 8; ++mm) {
    float g = 0.f;
#pragma unroll
    for (int jj = 0; jj < 8; ++jj) g += pv[c * 64 + mm * 8 + jj] * Bm[jj * 8 + fk];
    acc += Bm[fi * 8 + mm] * g;
  }
  F2[(size_t)blk * 192 + t] = f2b(acc);
}

// ---------------- spectral softmax: 1 block per row, 784 cols -> bf16 P (padded to 832) ----------------
__global__ __launch_bounds__(256) void spec_softmax(const float* __restrict__ S, u16* __restrict__ P)
{
  __shared__ float red[4];
  int row = blockIdx.x;
  const float* sr = S + (size_t)row * 784;
  u16* pr = P + (size_t)row * 832;
  int t = threadIdx.x;
  int lane = t & 63, wid = t >> 6;
  float v0 = sr[t];
  float v1 = sr[t + 256];
  float v2 = (t < 272) ? sr[t + 512] : -1e30f;
  float m = fmaxf(fmaxf(v0, v1), v2);
#pragma unroll
  for (int ofs = 32; ofs > 0; ofs >>= 1) m = fmaxf(m, __shfl_xor(m, ofs));
  if (lane == 0) red[wid] = m;
  __syncthreads();
  m = fmaxf(fmaxf(red[0], red[1]), fmaxf(red[2], red[3]));
  __syncthreads();
  const float scale = 0.044194173824159216f;  // 1/sqrt(512)
  float e0 = __expf((v0 - m) * scale);
  float e1 = __expf((v1 - m) * scale);
  float e2 = (t < 272) ? __expf((v2 - m) * scale) : 0.f;
  float sum = e0 + e1 + e2;
#pragma unroll
  for (int ofs = 32; ofs > 0; ofs >>= 1) sum += __shfl_xor(sum, ofs);
  if (lane == 0) red[wid] = sum;
  __syncthreads();
  sum = red[0] + red[1] + red[2] + red[3];
  float inv = 1.f / sum;
  pr[t] = f2b(e0 * inv);
  pr[t + 256] = f2b(e1 * inv);
  if (t < 272) pr[t + 512] = f2b(e2 * inv);
  else if (t < 320) pr[t + 512] = 0;  // pad 784..831
}

// ---------------- V transpose for PV gemm: Vt[b][n][k] = V[b][k][n], k padded to 832 ----------------
__global__ __launch_bounds__(256) void transV(const u16* __restrict__ qkvs, u16* __restrict__ Vt)
{
  int idx = blockIdx.x * 256 + threadIdx.x;  // 4*512*832
  int k = idx % 832;
  int rest = idx / 832;
  int n = rest % 512, b = rest / 512;
  u16 v = 0;
  if (k < 784) v = qkvs[((size_t)(b * 784 + k)) * 1536 + 1024 + n];
  Vt[idx] = v;
}

// ---------------- combine + nearest-upsample gather + LayerNorm ----------------
__global__ __launch_bounds__(256) void combine_ln(
    const float* __restrict__ tokens, const u16* __restrict__ sp,
    const float* __restrict__ so, const float* __restrict__ alpha,
    float* __restrict__ out)
{
  int nidx = blockIdx.x;
  int b = nidx / 12544, pos = nidx % 12544;
  int i = pos / 112, j = pos % 112;
  const float* tr = tokens + (size_t)nidx * 512;
  const u16* sr = sp + (size_t)nidx * 512;
  const float* qr = so + (size_t)(b * 784 + (i >> 2) * 28 + (j >> 2)) * 512;
  float al = 1.f / (1.f + __expf(-alpha[0]));
  float be = 1.f - al;
  int t = threadIdx.x;
  float x0 = tr[t] + al * b2f(sr[t]) + be * qr[t];
  float x1 = tr[t + 256] + al * b2f(sr[t + 256]) + be * qr[t + 256];
  float s = x0 + x1, ss = x0 * x0 + x1 * x1;
#pragma unroll
  for (int ofs = 32; ofs > 0; ofs >>= 1) { s += __shfl_xor(s, ofs); ss += __shfl_xor(ss, ofs); }
  __shared__ float rs[4], rq[4];
  int lane = t & 63, wid = t >> 6;
  if (lane == 0) { rs[wid] = s; rq[wid] = ss; }
  __syncthreads();
  s = rs[0] + rs[1] + rs[2] + rs[3];
  ss = rq[0] + rq[1] + rq[2] + rq[3];
  float mu = s * 0.001953125f;
  float var = ss * 0.001953125f - mu * mu;
  float rstd = rsqrtf(var + 1e-5f);
  float* orow = out + (size_t)nidx * 512;
  orow[t] = (x0 - mu) * rstd;
  orow[t + 256] = (x1 - mu) * rstd;
}

// ---------------- small prep kernels ----------------
__global__ __launch_bounds__(256) void transT(const float* __restrict__ src, u16* __restrict__ dst, int K, int Nc)
{
  int idx = blockIdx.x * 256 + threadIdx.x;
  if (idx >= K * Nc) return;
  int nn = idx / K, kk = idx % K;
  dst[idx] = f2b(src[(size_t)kk * Nc + nn]);
}

__global__ __launch_bounds__(256) void cvtbf(const float* __restrict__ src, u16* __restrict__ dst)
{
  size_t i = ((size_t)blockIdx.x * 256 + threadIdx.x) * 4;
  float4 v = *(const float4*)(src + i);
  uint2 u;
  u.x = pack2(v.x, v.y);
  u.y = pack2(v.z, v.w);
  *(uint2*)(dst + i) = u;
}

__global__ __launch_bounds__(256) void stack_bias(
    const float* bq_, const float* bk_, const float* bv_,
    const float* bsq_, const float* bsk_, const float* bsv_,
    float* bqkv, float* bsqkv)
{
  int i = blockIdx.x * 256 + threadIdx.x;
  if (i >= 1536) return;
  int r = i & 511;
  bqkv[i]  = (i < 512) ? bq_[r]  : (i < 1024) ? bk_[r]  : bv_[r];
  bsqkv[i] = (i < 512) ? bsq_[r] : (i < 1024) ? bsk_[r] : bsv_[r];
}

// ---------------- launch ----------------
extern "C" void kernel_launch(void* const* d_in, const int* in_sizes, int n_in,
                              void* d_out, int out_size, void* d_ws, size_t ws_size,
                              hipStream_t stream) {
  (void)in_sizes; (void)n_in; (void)out_size; (void)ws_size;
  const float* tokens = (const float*)d_in[0];
  const float* patches = (const float*)d_in[1];
  const float* Wq  = (const float*)d_in[2];
  const float* bq  = (const float*)d_in[3];
  const float* Wk  = (const float*)d_in[4];
  const float* bk  = (const float*)d_in[5];
  const float* Wv  = (const float*)d_in[6];
  const float* bv  = (const float*)d_in[7];
  const float* Wo  = (const float*)d_in[8];
  const float* bo  = (const float*)d_in[9];
  const float* Wsp = (const float*)d_in[10];
  const float* bsp = (const float*)d_in[11];
  const float* Wsq = (const float*)d_in[12];
  const float* bsq = (const float*)d_in[13];
  const float* Wsk = (const float*)d_in[14];
  const float* bsk = (const float*)d_in[15];
  const float* Wsv = (const float*)d_in[16];
  const float* bsv = (const float*)d_in[17];
  const float* Wso = (const float*)d_in[18];
  const float* bso = (const float*)d_in[19];
  const float* alpha = (const float*)d_in[20];
  float* out = (float*)d_out;

  char* ws = (char*)d_ws;
  u16* tokbf  = (u16*)ws;                       // 50176x512 bf16; dead after O-proj -> spec scratch
  u16* qkv    = (u16*)(ws + 51380224);          // 50176x1536 bf16 (later: sp_out 50176x512)
  char* pp    = ws + 51380224 + 154140672;
  u16* WqkvT  = (u16*)pp; pp += 1572864;
  u16* WoT    = (u16*)pp; pp += 524288;
  u16* WsqkvT = (u16*)pp; pp += 1572864;
  u16* WsoT   = (u16*)pp; pp += 524288;
  u16* WspT   = (u16*)pp; pp += 196608;
  float* bqkv = (float*)pp; pp += 6144;
  float* bsqkv= (float*)pp; pp += 6144;
  u16* F2b    = (u16*)pp; pp += 1204224;        // 3136x192 bf16
  u16* sd     = (u16*)pp; pp += 3211264;        // 3136x512 bf16
  u16* qkvs   = (u16*)pp; pp += 9633792;        // 3136x1536 bf16
  u16* sopre  = (u16*)pp; pp += 3211264;        // 3136x512 bf16
  float* sofin= (float*)pp; pp += 6422528;      // 3136x512 f32

  // spec-attn scratch aliases tokbf (dead after O-proj gemm)
  float* Sbuf = (float*)tokbf;                  // 4x784x784 f32 = 9.83 MB
  u16* Pbuf   = (u16*)(ws + 9834496);           // 4x784x832 bf16 = 5.22 MB
  u16* Vt     = (u16*)(ws + 9834496 + 5218304); // 4x512x832 bf16 = 3.41 MB

  // prep
  cvtbf<<<25088, 256, 0, stream>>>(tokens, tokbf);
  transT<<<1024, 256, 0, stream>>>(Wq, WqkvT, 512, 512);
  transT<<<1024, 256, 0, stream>>>(Wk, WqkvT + 262144, 512, 512);
  transT<<<1024, 256, 0, stream>>>(Wv, WqkvT + 524288, 512, 512);
  transT<<<1024, 256, 0, stream>>>(Wo, WoT, 512, 512);
  transT<<<1024, 256, 0, stream>>>(Wsq, WsqkvT, 512, 512);
  transT<<<1024, 256, 0, stream>>>(Wsk, WsqkvT + 262144, 512, 512);
  transT<<<1024, 256, 0, stream>>>(Wsv, WsqkvT + 524288, 512, 512);
  transT<<<1024, 256, 0, stream>>>(Wso, WsoT, 512, 512);
  transT<<<384, 256, 0, stream>>>(Wsp, WspT, 192, 512);
  stack_bias<<<6, 256, 0, stream>>>(bq, bk, bv, bsq, bsk, bsv, bqkv, bsqkv);

  // spatial path
  gemm_bt<<<dim3(12, 392), 256, 0, stream>>>(tokbf, 512, 0, WqkvT, 512, 0, bqkv, qkv, 1536, 0, 50176, 1536, 512, 1);
  win_attn<<<16384, 64, 0, stream>>>(qkv, tokbf);
  gemm_bt<<<dim3(4, 392), 256, 0, stream>>>(tokbf, 512, 0, WoT, 512, 0, bo, qkv, 512, 0, 50176, 512, 512, 1);

  // spectral path (only subsampled 3136 positions matter)
  dct_f2<<<3136, 192, 0, stream>>>(patches, F2b);
  gemm_bt<<<dim3(4, 25), 256, 0, stream>>>(F2b, 192, 0, WspT, 192, 0, bsp, sd, 512, 0, 3136, 512, 192, 1);
  gemm_bt<<<dim3(12, 25), 256, 0, stream>>>(sd, 512, 0, WsqkvT, 512, 0, bsqkv, qkvs, 1536, 0, 3136, 1536, 512, 1);
  // spectral attention via MFMA: S = Qs Ks^T, softmax, O = P V
  gemm_bt<<<dim3(7, 7, 4), 256, 0, stream>>>(qkvs, 1536, (long)784 * 1536, qkvs + 512, 1536, (long)784 * 1536,
                                             nullptr, Sbuf, 784, (long)784 * 784, 784, 784, 512, 0);
  spec_softmax<<<3136, 256, 0, stream>>>(Sbuf, Pbuf);
  transV<<<6656, 256, 0, stream>>>(qkvs, Vt);
  gemm_bt<<<dim3(4, 7, 4), 256, 0, stream>>>(Pbuf, 832, (long)784 * 832, Vt, 832, (long)512 * 832,
                                             nullptr, sopre, 512, (long)784 * 512, 784, 512, 832, 1);
  gemm_bt<<<dim3(4, 25), 256, 0, stream>>>(sopre, 512, 0, WsoT, 512, 0, bso, sofin, 512, 0, 3136, 512, 512, 0);

  // combine + LN
  combine_ln<<<50176, 256, 0, stream>>>(tokens, qkv, sofin, alpha, out);
}

// Round 3
// 540.754 us; speedup vs baseline: 1.9215x; 1.3523x over previous
//
#include <hip/hip_runtime.h>

typedef unsigned short u16;
typedef __attribute__((ext_vector_type(4))) float f32x4;
typedef __attribute__((ext_vector_type(8))) short bf16x8;

#define AS1 __attribute__((address_space(1)))
#define AS3 __attribute__((address_space(3)))
#define GLL(gp, lp) __builtin_amdgcn_global_load_lds((const AS1 void*)(gp), (AS3 void*)(lp), 16, 0, 0)

__device__ __forceinline__ float b2f(u16 v) { return __uint_as_float(((unsigned)v) << 16); }
__device__ __forceinline__ u16 f2b(float f) {
  unsigned u = __float_as_uint(f);
  u += 0x7fffu + ((u >> 16) & 1u);
  return (u16)(u >> 16);
}
__device__ __forceinline__ unsigned pack2(float a, float b) {
  return (unsigned)f2b(a) | ((unsigned)f2b(b) << 16);
}
__device__ __forceinline__ float blo(unsigned u) { return __uint_as_float(u << 16); }
__device__ __forceinline__ float bhi(unsigned u) { return __uint_as_float(u & 0xffff0000u); }

// ---------------- bf16 GEMM: C[M,N] = A[M,K] * Bt[N,K]^T + bias, fp32 accum ----------------
__global__ __launch_bounds__(256) void gemm_bt(
    const u16* __restrict__ A, int lda, long sAb,
    const u16* __restrict__ Bt, int ldb, long sBb,
    const float* __restrict__ bias, void* __restrict__ Cv, int ldc, long sCb,
    int M, int N, int K, int c_bf16)
{
  __shared__ __align__(16) u16 ldsA[128 * 64];
  __shared__ __align__(16) u16 ldsB[128 * 64];
  int tid = threadIdx.x;
  int wid = tid >> 6, lane = tid & 63;
  int row0 = blockIdx.y << 7;
  int col0 = blockIdx.x << 7;
  int bz = blockIdx.z;
  A += (size_t)bz * sAb;
  Bt += (size_t)bz * sBb;
  int wr = (wid >> 1) << 6, wc = (wid & 1) << 6;

  f32x4 acc[4][4];
#pragma unroll
  for (int i = 0; i < 4; ++i)
#pragma unroll
    for (int j = 0; j < 4; ++j) { f32x4 z = {0.f, 0.f, 0.f, 0.f}; acc[i][j] = z; }

  for (int kt = 0; kt < K; kt += 64) {
#pragma unroll
    for (int q = 0; q < 4; ++q) {
      int inst = (wid << 2) + q;
      int o = (inst << 10) + (lane << 4);
      int r = o >> 7;
      int cs = (o >> 4) & 7;
      int cl = cs ^ (r & 7);
      int ar = row0 + r; ar = ar < M ? ar : M - 1;
      GLL(A + (size_t)ar * lda + kt + (cl << 3), ldsA + (inst << 9));
      int br = col0 + r; br = br < N ? br : N - 1;
      GLL(Bt + (size_t)br * ldb + kt + (cl << 3), ldsB + (inst << 9));
    }
    __syncthreads();
#pragma unroll
    for (int kk = 0; kk < 2; ++kk) {
      bf16x8 af[4], bg[4];
#pragma unroll
      for (int mi = 0; mi < 4; ++mi) {
        int r = wr + (mi << 4) + (lane & 15);
        int cs = ((kk << 2) + (lane >> 4)) ^ (r & 7);
        af[mi] = *(const bf16x8*)(ldsA + (r << 6) + (cs << 3));
      }
#pragma unroll
      for (int ni = 0; ni < 4; ++ni) {
        int r = wc + (ni << 4) + (lane & 15);
        int cs = ((kk << 2) + (lane >> 4)) ^ (r & 7);
        bg[ni] = *(const bf16x8*)(ldsB + (r << 6) + (cs << 3));
      }
#pragma unroll
      for (int mi = 0; mi < 4; ++mi)
#pragma unroll
        for (int ni = 0; ni < 4; ++ni)
          acc[mi][ni] = __builtin_amdgcn_mfma_f32_16x16x32_bf16(af[mi], bg[ni], acc[mi][ni], 0, 0, 0);
    }
    __syncthreads();
  }

#pragma unroll
  for (int mi = 0; mi < 4; ++mi) {
    int rb = row0 + wr + (mi << 4) + ((lane >> 4) << 2);
#pragma unroll
    for (int ni = 0; ni < 4; ++ni) {
      int c = col0 + wc + (ni << 4) + (lane & 15);
      float bv = (bias && c < N) ? bias[c] : 0.f;
#pragma unroll
      for (int j = 0; j < 4; ++j) {
        int r = rb + j;
        if (r < M && c < N) {
          float v = acc[mi][ni][j] + bv;
          if (c_bf16) ((u16*)Cv)[(size_t)bz * sCb + (size_t)r * ldc + c] = f2b(v);
          else ((float*)Cv)[(size_t)bz * sCb + (size_t)r * ldc + c] = v;
        }
      }
    }
  }
}

// ---------------- window attention via MFMA: 1 block per window, wave = head group ----------------
// L=49 padded to 64, HD=32. Q/K fragments load straight from global (qkv layout is K-contiguous).
// S = QK^T as 4x4 16x16x32 MFMA tiles; in-register softmax (16-lane shfl reduce, deferred norm);
// P (bf16) -> per-wave LDS [64][72]; V staged transposed [32][72]; O = PV as 4x2x2 MFMAs.
__global__ __launch_bounds__(256, 2) void win_attn_mfma(const u16* __restrict__ qkv, u16* __restrict__ oat)
{
  __shared__ __align__(16) u16 Pl[4][64 * 72];
  __shared__ __align__(16) u16 Vtl[4][32 * 72];
  int tid = threadIdx.x;
  int wid = tid >> 6, lane = tid & 63;
  int lm = lane & 15, lg = lane >> 4;
  int w = blockIdx.x;
  int b = w >> 8, wh = (w >> 4) & 15, ww = w & 15;
  int rowbase = (wh * 7) * 112 + ww * 7;   // n = rowbase + (i/7)*112 + i%7
  u16* P = Pl[wid];
  u16* Vt = Vtl[wid];
  const u16* base = qkv + (size_t)b * 12544 * 1536;
  u16* ob = oat + (size_t)b * 12544 * 512;
  const float scale = 0.17677669529663687f;  // 1/sqrt(32)

  for (int hh = 0; hh < 4; ++hh) {
    int h = wid * 4 + hh;
    // ---- Q,K fragments direct from global (row = lm, k-chunk = lg*8) ----
    bf16x8 Qf[4], Kf[4];
#pragma unroll
    for (int mi = 0; mi < 4; ++mi) {
      int i = mi * 16 + lm; i = i < 49 ? i : 48;
      int q7 = (i * 147) >> 10;
      int n = rowbase + q7 * 112 + (i - q7 * 7);
      const u16* rp = base + (size_t)n * 1536 + h * 32 + lg * 8;
      Qf[mi] = *(const bf16x8*)(rp);
      Kf[mi] = *(const bf16x8*)(rp + 512);
    }
    // ---- stage V transposed: Vt[d][j], zeros for j>=49 ----
    {
      int j = lane;
      if (j < 49) {
        int q7 = (j * 147) >> 10;
        int n = rowbase + q7 * 112 + (j - q7 * 7);
        const uint4* vp = (const uint4*)(base + (size_t)n * 1536 + 1024 + h * 32);
#pragma unroll
        for (int t = 0; t < 4; ++t) {
          uint4 u = vp[t];
          Vt[(t * 8 + 0) * 72 + j] = (u16)(u.x & 0xffff); Vt[(t * 8 + 1) * 72 + j] = (u16)(u.x >> 16);
          Vt[(t * 8 + 2) * 72 + j] = (u16)(u.y & 0xffff); Vt[(t * 8 + 3) * 72 + j] = (u16)(u.y >> 16);
          Vt[(t * 8 + 4) * 72 + j] = (u16)(u.z & 0xffff); Vt[(t * 8 + 5) * 72 + j] = (u16)(u.z >> 16);
          Vt[(t * 8 + 6) * 72 + j] = (u16)(u.w & 0xffff); Vt[(t * 8 + 7) * 72 + j] = (u16)(u.w >> 16);
        }
      } else {
#pragma unroll
        for (int d = 0; d < 32; ++d) Vt[d * 72 + j] = 0;
      }
    }
    // ---- S = Q K^T ----
    f32x4 S[4][4];
#pragma unroll
    for (int mi = 0; mi < 4; ++mi)
#pragma unroll
      for (int nj = 0; nj < 4; ++nj) { f32x4 z = {0.f, 0.f, 0.f, 0.f}; S[mi][nj] = z; }
#pragma unroll
    for (int mi = 0; mi < 4; ++mi)
#pragma unroll
      for (int nj = 0; nj < 4; ++nj)
        S[mi][nj] = __builtin_amdgcn_mfma_f32_16x16x32_bf16(Qf[mi], Kf[nj], S[mi][nj], 0, 0, 0);
    // ---- softmax (rows spread over 16-lane group; cols: nj*16+lm, only nj=3&lm>0 invalid) ----
    float invv[4][4];
#pragma unroll
    for (int mi = 0; mi < 4; ++mi) {
#pragma unroll
      for (int reg = 0; reg < 4; ++reg) {
        float v0 = S[mi][0][reg], v1 = S[mi][1][reg], v2 = S[mi][2][reg], v3 = S[mi][3][reg];
        if (lm) v3 = -1e30f;
        float m = fmaxf(fmaxf(v0, v1), fmaxf(v2, v3));
#pragma unroll
        for (int o = 1; o < 16; o <<= 1) m = fmaxf(m, __shfl_xor(m, o));
        float e0 = __expf((v0 - m) * scale);
        float e1 = __expf((v1 - m) * scale);
        float e2 = __expf((v2 - m) * scale);
        float e3 = lm ? 0.f : __expf((v3 - m) * scale);
        float s = e0 + e1 + e2 + e3;
#pragma unroll
        for (int o = 1; o < 16; o <<= 1) s += __shfl_xor(s, o);
        invv[mi][reg] = 1.f / s;
        int r = mi * 16 + lg * 4 + reg;
        P[r * 72 + lm] = f2b(e0);
        P[r * 72 + 16 + lm] = f2b(e1);
        P[r * 72 + 32 + lm] = f2b(e2);
        P[r * 72 + 48 + lm] = f2b(e3);
      }
    }
    // ---- O = P V ----
    bf16x8 Vf[2][2];
#pragma unroll
    for (int dt = 0; dt < 2; ++dt) {
      Vf[dt][0] = *(const bf16x8*)(Vt + (dt * 16 + lm) * 72 + lg * 8);
      Vf[dt][1] = *(const bf16x8*)(Vt + (dt * 16 + lm) * 72 + 32 + lg * 8);
    }
    f32x4 O[4][2];
#pragma unroll
    for (int mi = 0; mi < 4; ++mi)
#pragma unroll
      for (int dt = 0; dt < 2; ++dt) { f32x4 z = {0.f, 0.f, 0.f, 0.f}; O[mi][dt] = z; }
#pragma unroll
    for (int mi = 0; mi < 4; ++mi) {
      bf16x8 Pf0 = *(const bf16x8*)(P + (mi * 16 + lm) * 72 + lg * 8);
      bf16x8 Pf1 = *(const bf16x8*)(P + (mi * 16 + lm) * 72 + 32 + lg * 8);
#pragma unroll
      for (int dt = 0; dt < 2; ++dt) {
        O[mi][dt] = __builtin_amdgcn_mfma_f32_16x16x32_bf16(Pf0, Vf[dt][0], O[mi][dt], 0, 0, 0);
        O[mi][dt] = __builtin_amdgcn_mfma_f32_16x16x32_bf16(Pf1, Vf[dt][1], O[mi][dt], 0, 0, 0);
      }
    }
    // ---- write O (rows i<49), deferred softmax normalization ----
#pragma unroll
    for (int mi = 0; mi < 4; ++mi)
#pragma unroll
      for (int reg = 0; reg < 4; ++reg) {
        int i = mi * 16 + lg * 4 + reg;
        if (i < 49) {
          int q7 = (i * 147) >> 10;
          int n = rowbase + q7 * 112 + (i - q7 * 7);
          float iv = invv[mi][reg];
          u16* op = ob + (size_t)n * 512 + h * 32 + lm;
          op[0] = f2b(O[mi][0][reg] * iv);
          op[16] = f2b(O[mi][1][reg] * iv);
        }
      }
  }
}

// ---------------- DCT of 8x8 patches at subsampled positions -> F2 (3136 x 192) bf16 ----------------
__global__ __launch_bounds__(192) void dct_f2(const float* __restrict__ patches, u16* __restrict__ F2)
{
  __shared__ float pv[192];
  __shared__ float Bm[64];
  int blk = blockIdx.x;
  int b = blk / 784, rem = blk % 784;
  int n = ((rem / 28) * 4) * 112 + (rem % 28) * 4;
  int t = threadIdx.x;
  if (t < 64) {
    int k = t >> 3, ii = t & 7;
    float v = cosf(3.14159265358979323846f * (ii + 0.5f) * (float)k * 0.125f) * 0.5f;
    if (k == 0) v *= 0.70710678118654752f;
    Bm[t] = v;  // Bm[k*8 + i]
  }
  pv[t] = patches[((size_t)b * 192 + t) * 12544 + n];
  __syncthreads();
  int c = t >> 6, fi = (t >> 3) & 7, fk = t & 7;
  float acc = 0.f;
#pragma unroll
  for (int mm = 0; mm < 8; ++mm) {
    float g = 0.f;
#pragma unroll
    for (int jj = 0; jj < 8; ++jj) g += pv[c * 64 + mm * 8 + jj] * Bm[jj * 8 + fk];
    acc += Bm[fi * 8 + mm] * g;
  }
  F2[(size_t)blk * 192 + t] = f2b(acc);
}

// ---------------- spectral softmax: 1 block per row, 784 cols -> bf16 P (padded to 832) ----------------
__global__ __launch_bounds__(256) void spec_softmax(const float* __restrict__ S, u16* __restrict__ P)
{
  __shared__ float red[4];
  int row = blockIdx.x;
  const float* sr = S + (size_t)row * 784;
  u16* pr = P + (size_t)row * 832;
  int t = threadIdx.x;
  int lane = t & 63, wid = t >> 6;
  float v0 = sr[t];
  float v1 = sr[t + 256];
  float v2 = (t < 272) ? sr[t + 512] : -1e30f;
  float m = fmaxf(fmaxf(v0, v1), v2);
#pragma unroll
  for (int ofs = 32; ofs > 0; ofs >>= 1) m = fmaxf(m, __shfl_xor(m, ofs));
  if (lane == 0) red[wid] = m;
  __syncthreads();
  m = fmaxf(fmaxf(red[0], red[1]), fmaxf(red[2], red[3]));
  __syncthreads();
  const float scale = 0.044194173824159216f;  // 1/sqrt(512)
  float e0 = __expf((v0 - m) * scale);
  float e1 = __expf((v1 - m) * scale);
  float e2 = (t < 272) ? __expf((v2 - m) * scale) : 0.f;
  float sum = e0 + e1 + e2;
#pragma unroll
  for (int ofs = 32; ofs > 0; ofs >>= 1) sum += __shfl_xor(sum, ofs);
  if (lane == 0) red[wid] = sum;
  __syncthreads();
  sum = red[0] + red[1] + red[2] + red[3];
  float inv = 1.f / sum;
  pr[t] = f2b(e0 * inv);
  pr[t + 256] = f2b(e1 * inv);
  if (t < 272) pr[t + 512] = f2b(e2 * inv);
  else if (t < 320) pr[t + 512] = 0;  // pad 784..831
}

// ---------------- V transpose for PV gemm: Vt[b][n][k] = V[b][k][n], k padded to 832 ----------------
__global__ __launch_bounds__(256) void transV(const u16* __restrict__ qkvs, u16* __restrict__ Vt)
{
  int idx = blockIdx.x * 256 + threadIdx.x;  // 4*512*832
  int k = idx % 832;
  int rest = idx / 832;
  int n = rest % 512, b = rest / 512;
  u16 v = 0;
  if (k < 784) v = qkvs[((size_t)(b * 784 + k)) * 1536 + 1024 + n];
  Vt[idx] = v;
}

// ---------------- combine + nearest-upsample gather + LayerNorm ----------------
__global__ __launch_bounds__(256) void combine_ln(
    const float* __restrict__ tokens, const u16* __restrict__ sp,
    const float* __restrict__ so, const float* __restrict__ alpha,
    float* __restrict__ out)
{
  int nidx = blockIdx.x;
  int b = nidx / 12544, pos = nidx % 12544;
  int i = pos / 112, j = pos % 112;
  const float* tr = tokens + (size_t)nidx * 512;
  const u16* sr = sp + (size_t)nidx * 512;
  const float* qr = so + (size_t)(b * 784 + (i >> 2) * 28 + (j >> 2)) * 512;
  float al = 1.f / (1.f + __expf(-alpha[0]));
  float be = 1.f - al;
  int t = threadIdx.x;
  float x0 = tr[t] + al * b2f(sr[t]) + be * qr[t];
  float x1 = tr[t + 256] + al * b2f(sr[t + 256]) + be * qr[t + 256];
  float s = x0 + x1, ss = x0 * x0 + x1 * x1;
#pragma unroll
  for (int ofs = 32; ofs > 0; ofs >>= 1) { s += __shfl_xor(s, ofs); ss += __shfl_xor(ss, ofs); }
  __shared__ float rs[4], rq[4];
  int lane = t & 63, wid = t >> 6;
  if (lane == 0) { rs[wid] = s; rq[wid] = ss; }
  __syncthreads();
  s = rs[0] + rs[1] + rs[2] + rs[3];
  ss = rq[0] + rq[1] + rq[2] + rq[3];
  float mu = s * 0.001953125f;
  float var = ss * 0.001953125f - mu * mu;
  float rstd = rsqrtf(var + 1e-5f);
  float* orow = out + (size_t)nidx * 512;
  orow[t] = (x0 - mu) * rstd;
  orow[t + 256] = (x1 - mu) * rstd;
}

// ---------------- small prep kernels ----------------
__global__ __launch_bounds__(256) void transT(const float* __restrict__ src, u16* __restrict__ dst, int K, int Nc)
{
  int idx = blockIdx.x * 256 + threadIdx.x;
  if (idx >= K * Nc) return;
  int nn = idx / K, kk = idx % K;
  dst[idx] = f2b(src[(size_t)kk * Nc + nn]);
}

__global__ __launch_bounds__(256) void cvtbf(const float* __restrict__ src, u16* __restrict__ dst)
{
  size_t i = ((size_t)blockIdx.x * 256 + threadIdx.x) * 4;
  float4 v = *(const float4*)(src + i);
  uint2 u;
  u.x = pack2(v.x, v.y);
  u.y = pack2(v.z, v.w);
  *(uint2*)(dst + i) = u;
}

__global__ __launch_bounds__(256) void stack_bias(
    const float* bq_, const float* bk_, const float* bv_,
    const float* bsq_, const float* bsk_, const float* bsv_,
    float* bqkv, float* bsqkv)
{
  int i = blockIdx.x * 256 + threadIdx.x;
  if (i >= 1536) return;
  int r = i & 511;
  bqkv[i]  = (i < 512) ? bq_[r]  : (i < 1024) ? bk_[r]  : bv_[r];
  bsqkv[i] = (i < 512) ? bsq_[r] : (i < 1024) ? bsk_[r] : bsv_[r];
}

// ---------------- launch ----------------
extern "C" void kernel_launch(void* const* d_in, const int* in_sizes, int n_in,
                              void* d_out, int out_size, void* d_ws, size_t ws_size,
                              hipStream_t stream) {
  (void)in_sizes; (void)n_in; (void)out_size; (void)ws_size;
  const float* tokens = (const float*)d_in[0];
  const float* patches = (const float*)d_in[1];
  const float* Wq  = (const float*)d_in[2];
  const float* bq  = (const float*)d_in[3];
  const float* Wk  = (const float*)d_in[4];
  const float* bk  = (const float*)d_in[5];
  const float* Wv  = (const float*)d_in[6];
  const float* bv  = (const float*)d_in[7];
  const float* Wo  = (const float*)d_in[8];
  const float* bo  = (const float*)d_in[9];
  const float* Wsp = (const float*)d_in[10];
  const float* bsp = (const float*)d_in[11];
  const float* Wsq = (const float*)d_in[12];
  const float* bsq = (const float*)d_in[13];
  const float* Wsk = (const float*)d_in[14];
  const float* bsk = (const float*)d_in[15];
  const float* Wsv = (const float*)d_in[16];
  const float* bsv = (const float*)d_in[17];
  const float* Wso = (const float*)d_in[18];
  const float* bso = (const float*)d_in[19];
  const float* alpha = (const float*)d_in[20];
  float* out = (float*)d_out;

  char* ws = (char*)d_ws;
  u16* tokbf  = (u16*)ws;                       // 50176x512 bf16; dead after O-proj -> spec scratch
  u16* qkv    = (u16*)(ws + 51380224);          // 50176x1536 bf16 (later: sp_out 50176x512)
  char* pp    = ws + 51380224 + 154140672;
  u16* WqkvT  = (u16*)pp; pp += 1572864;
  u16* WoT    = (u16*)pp; pp += 524288;
  u16* WsqkvT = (u16*)pp; pp += 1572864;
  u16* WsoT   = (u16*)pp; pp += 524288;
  u16* WspT   = (u16*)pp; pp += 196608;
  float* bqkv = (float*)pp; pp += 6144;
  float* bsqkv= (float*)pp; pp += 6144;
  u16* F2b    = (u16*)pp; pp += 1204224;        // 3136x192 bf16
  u16* sd     = (u16*)pp; pp += 3211264;        // 3136x512 bf16
  u16* qkvs   = (u16*)pp; pp += 9633792;        // 3136x1536 bf16
  u16* sopre  = (u16*)pp; pp += 3211264;        // 3136x512 bf16
  float* sofin= (float*)pp; pp += 6422528;      // 3136x512 f32

  // spec-attn scratch aliases tokbf (dead after O-proj gemm)
  float* Sbuf = (float*)tokbf;                  // 4x784x784 f32 = 9.83 MB
  u16* Pbuf   = (u16*)(ws + 9834496);           // 4x784x832 bf16 = 5.22 MB
  u16* Vt     = (u16*)(ws + 9834496 + 5218304); // 4x512x832 bf16 = 3.41 MB

  // prep
  cvtbf<<<25088, 256, 0, stream>>>(tokens, tokbf);
  transT<<<1024, 256, 0, stream>>>(Wq, WqkvT, 512, 512);
  transT<<<1024, 256, 0, stream>>>(Wk, WqkvT + 262144, 512, 512);
  transT<<<1024, 256, 0, stream>>>(Wv, WqkvT + 524288, 512, 512);
  transT<<<1024, 256, 0, stream>>>(Wo, WoT, 512, 512);
  transT<<<1024, 256, 0, stream>>>(Wsq, WsqkvT, 512, 512);
  transT<<<1024, 256, 0, stream>>>(Wsk, WsqkvT + 262144, 512, 512);
  transT<<<1024, 256, 0, stream>>>(Wsv, WsqkvT + 524288, 512, 512);
  transT<<<1024, 256, 0, stream>>>(Wso, WsoT, 512, 512);
  transT<<<384, 256, 0, stream>>>(Wsp, WspT, 192, 512);
  stack_bias<<<6, 256, 0, stream>>>(bq, bk, bv, bsq, bsk, bsv, bqkv, bsqkv);

  // spatial path
  gemm_bt<<<dim3(12, 392), 256, 0, stream>>>(tokbf, 512, 0, WqkvT, 512, 0, bqkv, qkv, 1536, 0, 50176, 1536, 512, 1);
  win_attn_mfma<<<1024, 256, 0, stream>>>(qkv, tokbf);
  gemm_bt<<<dim3(4, 392), 256, 0, stream>>>(tokbf, 512, 0, WoT, 512, 0, bo, qkv, 512, 0, 50176, 512, 512, 1);

  // spectral path (only subsampled 3136 positions matter)
  dct_f2<<<3136, 192, 0, stream>>>(patches, F2b);
  gemm_bt<<<dim3(4, 25), 256, 0, stream>>>(F2b, 192, 0, WspT, 192, 0, bsp, sd, 512, 0, 3136, 512, 192, 1);
  gemm_bt<<<dim3(12, 25), 256, 0, stream>>>(sd, 512, 0, WsqkvT, 512, 0, bsqkv, qkvs, 1536, 0, 3136, 1536, 512, 1);
  // spectral attention via MFMA: S = Qs Ks^T, softmax, O = P V
  gemm_bt<<<dim3(7, 7, 4), 256, 0, stream>>>(qkvs, 1536, (long)784 * 1536, qkvs + 512, 1536, (long)784 * 1536,
                                             nullptr, Sbuf, 784, (long)784 * 784, 784, 784, 512, 0);
  spec_softmax<<<3136, 256, 0, stream>>>(Sbuf, Pbuf);
  transV<<<6656, 256, 0, stream>>>(qkvs, Vt);
  gemm_bt<<<dim3(4, 7, 4), 256, 0, stream>>>(Pbuf, 832, (long)784 * 832, Vt, 832, (long)512 * 832,
                                             nullptr, sopre, 512, (long)784 * 512, 784, 512, 832, 1);
  gemm_bt<<<dim3(4, 25), 256, 0, stream>>>(sopre, 512, 0, WsoT, 512, 0, bso, sofin, 512, 0, 3136, 512, 512, 0);

  // combine + LN
  combine_ln<<<50176, 256, 0, stream>>>(tokens, qkv, sofin, alpha, out);
}